// Round 2
// baseline (1248.754 us; speedup 1.0000x reference)
//
#include <hip/hip_runtime.h>
#include <hip/hip_bf16.h>
#include <type_traits>

using bf16 = __hip_bfloat16;
typedef short v8s __attribute__((ext_vector_type(8)));
typedef float v4f __attribute__((ext_vector_type(4)));

#define DEV __device__ __forceinline__

constexpr float SCALE_ = 0.07216878364870322f;  // (128+64)^-0.5

DEV unsigned short bfu(float f) {
  bf16 h = __float2bfloat16(f);
  return __builtin_bit_cast(unsigned short, h);
}
DEV float b2f(short u) {
  unsigned int x = ((unsigned int)(unsigned short)u) << 16;
  return __builtin_bit_cast(float, x);
}

DEV void g2lds16(const void* g, void* l) {
  __builtin_amdgcn_global_load_lds(
      (const __attribute__((address_space(1))) unsigned int*)g,
      (__attribute__((address_space(3))) unsigned int*)l, 16, 0, 0);
}

// ---------------- elementwise / prep kernels ----------------

__global__ void cast_kernel(const float* __restrict__ in, bf16* __restrict__ out, int n4) {
  int i = blockIdx.x * 256 + threadIdx.x;
  int stride = gridDim.x * 256;
  for (; i < n4; i += stride) {
    float4 v = ((const float4*)in)[i];
    ushort4 u;
    u.x = bfu(v.x); u.y = bfu(v.y); u.z = bfu(v.z); u.w = bfu(v.w);
    ((ushort4*)out)[i] = u;
  }
}

// wkv_a (576,4096) f32 -> (640,4096) bf16 zero-padded
__global__ void cast_pad_kernel(const float* __restrict__ in, bf16* __restrict__ out) {
  int i = blockIdx.x * 256 + threadIdx.x;  // 655360 float4 groups
  float4 v = make_float4(0.f, 0.f, 0.f, 0.f);
  if (i < 589824) v = ((const float4*)in)[i];  // 576*4096/4
  ushort4 u;
  u.x = bfu(v.x); u.y = bfu(v.y); u.z = bfu(v.z); u.w = bfu(v.w);
  ((ushort4*)out)[i] = u;
}

// wkv_b (8192,512) f32 -> per-head transposed nope part: out[h][c][d] = wkv_b[h*256+d][c]
__global__ void wkvbt_kernel(const float* __restrict__ wkvb, bf16* __restrict__ out) {
  int i = blockIdx.x * 256 + threadIdx.x;  // 32*512*128
  int d = i & 127, c = (i >> 7) & 511, h = i >> 16;
  out[i] = __float2bfloat16(wkvb[(h * 256 + d) * 512 + c]);
}

// wkv_b v-part: out[h*128+d][c] = wkv_b[(h*256+128+d)][c], bf16
__global__ void wkvbv_kernel(const float* __restrict__ wkvb, bf16* __restrict__ out) {
  int i = blockIdx.x * 256 + threadIdx.x;  // 524288 float4 groups
  int c4 = i & 127, d = (i >> 7) & 127, h = i >> 14;
  float4 v = *(const float4*)(wkvb + ((long)(h * 256 + 128 + d)) * 512 + c4 * 4);
  ushort4 u;
  u.x = bfu(v.x); u.y = bfu(v.y); u.z = bfu(v.z); u.w = bfu(v.w);
  *(ushort4*)(out + ((long)(h * 128 + d)) * 512 + c4 * 4) = u;
}

__global__ void freqs_kernel(float* __restrict__ cosb, float* __restrict__ sinb) {
  int t = blockIdx.x * 256 + threadIdx.x;  // 2048*32
  int s = t >> 5, i = t & 31;
  float inv = powf(10000.0f, -(float)(2 * i) / 64.0f);
  float f = (float)s * inv;
  cosb[t] = cosf(f);
  sinb[t] = sinf(f);
}

// rmsnorm over bf16 rows, f32 weight, bf16 out
__global__ void rmsnorm_bf_kernel(const bf16* __restrict__ in, const float* __restrict__ w,
                                  bf16* __restrict__ out, int L, int ldin, int ldout) {
  int row = blockIdx.x;
  const bf16* x = in + (long)row * ldin;
  int L8 = L >> 3;
  float ss = 0.f;
  for (int i = threadIdx.x; i < L8; i += 256) {
    v8s v = *(const v8s*)(x + i * 8);
#pragma unroll
    for (int j = 0; j < 8; ++j) { float f = b2f(v[j]); ss += f * f; }
  }
#pragma unroll
  for (int d = 1; d < 64; d <<= 1) ss += __shfl_xor(ss, d);
  __shared__ float red[4];
  if ((threadIdx.x & 63) == 0) red[threadIdx.x >> 6] = ss;
  __syncthreads();
  float r = rsqrtf((red[0] + red[1] + red[2] + red[3]) / (float)L + 1e-6f);
  bf16* o = out + (long)row * ldout;
  for (int i = threadIdx.x; i < L8; i += 256) {
    v8s v = *(const v8s*)(x + i * 8);
    v8s u;
#pragma unroll
    for (int j = 0; j < 8; ++j)
      u[j] = (short)bfu(b2f(v[j]) * r * w[i * 8 + j]);
    *(v8s*)(o + i * 8) = u;
  }
}

// k_pe rope: kvall (S,640) bf16 cols 512..575 -> keff (S,576) bf16 cols 512..575
__global__ void rope_kpe_kernel(const bf16* __restrict__ kvall, const float* __restrict__ cosb,
                                const float* __restrict__ sinb, bf16* __restrict__ keff) {
  int t = blockIdx.x * 256 + threadIdx.x;  // 2048*32
  int s = t >> 5, i = t & 31;
  const bf16* p = kvall + (long)s * 640 + 512;
  float x0 = __bfloat162float(p[2 * i]), x1 = __bfloat162float(p[2 * i + 1]);
  float c = cosb[t], sn = sinb[t];
  bf16* o = keff + (long)s * 576 + 512;
  o[2 * i] = __float2bfloat16(x0 * c - x1 * sn);
  o[2 * i + 1] = __float2bfloat16(x0 * sn + x1 * c);
}

// q nope: qf (S,32,192) bf16 cols 0..127 -> qnope (S,32,128) bf16 (pure copy)
__global__ void qnope_cast_kernel(const bf16* __restrict__ qf, bf16* __restrict__ qnope) {
  int i = blockIdx.x * 256 + threadIdx.x;  // S*H*16, 8 elems each
  int d8 = i & 15, h = (i >> 4) & 31, s = i >> 9;
  *(v8s*)(qnope + (long)s * 4096 + h * 128 + d8 * 8) =
      *(const v8s*)(qf + (long)s * 6144 + h * 192 + d8 * 8);
}

// q_pe rope: qf (S,32,192) cols 128..191 -> qeff (S,32,576) cols 512..575
__global__ void rope_q_kernel(const bf16* __restrict__ qf, const float* __restrict__ cosb,
                              const float* __restrict__ sinb, bf16* __restrict__ qeff) {
  int t = blockIdx.x * 256 + threadIdx.x;  // S*H*32
  int i = t & 31, h = (t >> 5) & 31, s = t >> 10;
  const bf16* p = qf + (long)s * 6144 + h * 192 + 128;
  float x0 = __bfloat162float(p[2 * i]), x1 = __bfloat162float(p[2 * i + 1]);
  float c = cosb[s * 32 + i], sn = sinb[s * 32 + i];
  bf16* o = qeff + (long)s * 18432 + h * 576 + 512;
  o[2 * i] = __float2bfloat16(x0 * c - x1 * sn);
  o[2 * i + 1] = __float2bfloat16(x0 * sn + x1 * c);
}

// ---------------- GEMM: C = A @ B^T, A (M,K) bf16, B (N,K) bf16 ----------------
// 128x128 tile, BK=32, 4 waves (2x2), 4x4 16x16x32 frags per wave.
template <typename OutT>
__global__ __launch_bounds__(256, 2) void gemm_bt(
    const bf16* __restrict__ A, const bf16* __restrict__ B, OutT* __restrict__ C,
    int K, int lda, int ldb, int ldc, long sA, long sB, long sC) {
  __shared__ bf16 lA[4096];
  __shared__ bf16 lB[4096];
  const int tid = threadIdx.x;
  const int lane = tid & 63;
  const int w = tid >> 6, wm = w >> 1, wn = w & 1;
  const int r16 = lane & 15, kg = (lane >> 4) << 3;
  const int arow = tid >> 2, acol = (tid & 3) << 3;
  const bf16* Ab = A + (long)blockIdx.z * sA + (long)blockIdx.y * 128 * lda;
  const bf16* Bb = B + (long)blockIdx.z * sB + (long)blockIdx.x * 128 * ldb;
  v4f acc[4][4] = {};
  for (int k0 = 0; k0 < K; k0 += 32) {
    __syncthreads();
#pragma unroll
    for (int i = 0; i < 2; ++i) {
      g2lds16(Ab + (long)(i * 64 + arow) * lda + (k0 + acol), &lA[i * 2048 + w * 512]);
      g2lds16(Bb + (long)(i * 64 + arow) * ldb + (k0 + acol), &lB[i * 2048 + w * 512]);
    }
    __syncthreads();
    v8s af[4], bfr[4];
#pragma unroll
    for (int mi = 0; mi < 4; ++mi)
      af[mi] = *(const v8s*)&lA[(wm * 64 + mi * 16 + r16) * 32 + kg];
#pragma unroll
    for (int ni = 0; ni < 4; ++ni)
      bfr[ni] = *(const v8s*)&lB[(wn * 64 + ni * 16 + r16) * 32 + kg];
#pragma unroll
    for (int mi = 0; mi < 4; ++mi)
#pragma unroll
      for (int ni = 0; ni < 4; ++ni)
        acc[mi][ni] = __builtin_amdgcn_mfma_f32_16x16x32_bf16(af[mi], bfr[ni], acc[mi][ni], 0, 0, 0);
  }
  OutT* Cb = C + (long)blockIdx.z * sC + (long)(blockIdx.y * 128) * ldc + blockIdx.x * 128;
  const int cr = (lane >> 4) << 2;
#pragma unroll
  for (int mi = 0; mi < 4; ++mi)
#pragma unroll
    for (int ni = 0; ni < 4; ++ni)
#pragma unroll
      for (int j = 0; j < 4; ++j) {
        long idx = (long)(wm * 64 + mi * 16 + cr + j) * ldc + wn * 64 + ni * 16 + r16;
        float v = acc[mi][ni][j];
        if constexpr (std::is_same<OutT, float>::value) Cb[idx] = v;
        else Cb[idx] = __float2bfloat16(v);
      }
}

// ---------------- causal flash attention ----------------
// grid (32 qtiles, 32 heads), 256 thr. Block: 64 q rows. Waves own softmax for 16
// rows each; PV splits 512 V-cols across waves (wave w -> cols w*128..+128).
__global__ __launch_bounds__(256, 2) void attn_kernel(
    const bf16* __restrict__ qeff, const bf16* __restrict__ keff, bf16* __restrict__ olat) {
  constexpr int LD = 584;  // 576 + 8 pad (16B-aligned rows, 2-way banks)
  __shared__ bf16 kl[32 * LD];
  __shared__ bf16 pl[64 * 32];
  __shared__ float alf[64];
  const int tid = threadIdx.x, lane = tid & 63, w = tid >> 6;
  const int r16 = lane & 15, kg = (lane >> 4) << 3, cr = (lane >> 4) << 2;
  const int h = blockIdx.y;
  const int qt = gridDim.x - 1 - blockIdx.x;  // long blocks first

  const long qbase = (long)(qt * 64 + w * 16 + r16) * 18432 + h * 576;
  v8s qreg[18];
#pragma unroll
  for (int kk = 0; kk < 18; ++kk)
    qreg[kk] = *(const v8s*)(qeff + qbase + kk * 32 + kg);

  v4f acc[4][8] = {};
  float mrow[4] = {-1e30f, -1e30f, -1e30f, -1e30f};
  float lrow[4] = {0.f, 0.f, 0.f, 0.f};

  const int nch = 2 * qt + 2;
  for (int kc = 0; kc < nch; ++kc) {
    const int t0 = kc * 32;
    __syncthreads();  // prior-iter LDS reads complete
#pragma unroll
    for (int it = 0; it < 9; ++it) {
      int idx = it * 256 + tid;
      int row = idx / 72;
      int g = (idx - row * 72) << 3;
      v8s v = *(const v8s*)(keff + (long)(t0 + row) * 576 + g);
      *(v8s*)&kl[row * LD + g] = v;
    }
    __syncthreads();
    // ---- S = Q K^T for this wave's 16 rows, 32 kv cols ----
    v4f sf0 = {}, sf1 = {};
#pragma unroll
    for (int kk = 0; kk < 18; ++kk) {
      v8s b0 = *(const v8s*)&kl[r16 * LD + kk * 32 + kg];
      v8s b1 = *(const v8s*)&kl[(16 + r16) * LD + kk * 32 + kg];
      sf0 = __builtin_amdgcn_mfma_f32_16x16x32_bf16(qreg[kk], b0, sf0, 0, 0, 0);
      sf1 = __builtin_amdgcn_mfma_f32_16x16x32_bf16(qreg[kk], b1, sf1, 0, 0, 0);
    }
    // ---- online softmax (rows w*16+cr+j) ----
    float p0s[4], p1s[4], alpha[4];
#pragma unroll
    for (int j = 0; j < 4; ++j) {
      int sq = qt * 64 + w * 16 + cr + j;
      float s0 = (t0 + r16 > sq) ? -1e30f : sf0[j] * SCALE_;
      float s1 = (t0 + 16 + r16 > sq) ? -1e30f : sf1[j] * SCALE_;
      float mx = fmaxf(s0, s1);
#pragma unroll
      for (int d = 1; d < 16; d <<= 1) mx = fmaxf(mx, __shfl_xor(mx, d));
      float mn = fmaxf(mrow[j], mx);
      float a = __expf(mrow[j] - mn);
      float p0 = __expf(s0 - mn), p1 = __expf(s1 - mn);
      float rs = p0 + p1;
#pragma unroll
      for (int d = 1; d < 16; d <<= 1) rs += __shfl_xor(rs, d);
      lrow[j] = lrow[j] * a + rs;
      mrow[j] = mn;
      alpha[j] = a;
      p0s[j] = p0;
      p1s[j] = p1;
    }
    if (r16 == 0) {
#pragma unroll
      for (int j = 0; j < 4; ++j) alf[w * 16 + cr + j] = alpha[j];
    }
#pragma unroll
    for (int j = 0; j < 4; ++j) {
      pl[(w * 16 + cr + j) * 32 + r16] = __float2bfloat16(p0s[j]);
      pl[(w * 16 + cr + j) * 32 + 16 + r16] = __float2bfloat16(p1s[j]);
    }
    __syncthreads();  // P + alpha visible; all kl QK reads done
    // ---- rescale + PV: this wave covers all 64 rows x its 128 V cols ----
#pragma unroll
    for (int rb = 0; rb < 4; ++rb) {
      v8s pa = *(const v8s*)&pl[(rb * 16 + r16) * 32 + kg];
#pragma unroll
      for (int j = 0; j < 4; ++j) {
        float f = alf[rb * 16 + cr + j];
#pragma unroll
        for (int cfc = 0; cfc < 8; ++cfc) acc[rb][cfc][j] *= f;
      }
#pragma unroll
      for (int cfc = 0; cfc < 8; ++cfc) {
        int c = w * 128 + cfc * 16 + r16;
        v8s bv;
#pragma unroll
        for (int j2 = 0; j2 < 8; ++j2)
          bv[j2] = __builtin_bit_cast(short, kl[(kg + j2) * LD + c]);
        acc[rb][cfc] = __builtin_amdgcn_mfma_f32_16x16x32_bf16(pa, bv, acc[rb][cfc], 0, 0, 0);
      }
    }
  }
  // ---- epilogue: share l, normalize, store ----
  __syncthreads();
  if (r16 == 0) {
#pragma unroll
    for (int j = 0; j < 4; ++j) alf[w * 16 + cr + j] = lrow[j];
  }
  __syncthreads();
#pragma unroll
  for (int rb = 0; rb < 4; ++rb)
#pragma unroll
    for (int j = 0; j < 4; ++j) {
      float inv = 1.0f / alf[rb * 16 + cr + j];
      long rowb = (long)(qt * 64 + rb * 16 + cr + j) * 16384 + h * 512 + w * 128;
#pragma unroll
      for (int cfc = 0; cfc < 8; ++cfc)
        olat[rowb + cfc * 16 + r16] = __float2bfloat16(acc[rb][cfc][j] * inv);
    }
}

// ---------------- launch ----------------
// Workspace plan (peak 145.5 MB, temporally aliased; single stream => safe):
//   [0,           262144)   cosb
//   [262144,      524288)   sinb
//   BASE  = 524288          qeffb region (75,497,472) -> later wkvbv/obuf/wob
//   OLATR = 76021760        olat region  (67,108,864) -> earlier pipeline arena
//   KEFF  = 143130624       keff (2,359,296); total = 145,489,920 bytes

extern "C" void kernel_launch(void* const* d_in, const int* in_sizes, int n_in,
                              void* d_out, int out_size, void* d_ws, size_t ws_size,
                              hipStream_t stream) {
  const float* x = (const float*)d_in[0];
  const float* wq_a = (const float*)d_in[1];
  const float* q_norm_w = (const float*)d_in[2];
  const float* wq_b = (const float*)d_in[3];
  const float* wkv_a = (const float*)d_in[4];
  const float* kv_norm_w = (const float*)d_in[5];
  const float* wkv_b = (const float*)d_in[6];
  const float* wo = (const float*)d_in[7];
  char* ws = (char*)d_ws;

  float* cosb  = (float*)(ws + 0);
  float* sinb  = (float*)(ws + 262144);
  // long-lived
  bf16* qeffb  = (bf16*)(ws + 524288);      // 2048x32x576 (75.5MB), live rope_q..attn
  bf16* olat   = (bf16*)(ws + 76021760);    // 2048x32x512 (64MB), live attn..o-gemm
  bf16* keff   = (bf16*)(ws + 143130624);   // 2048x576, live norm..attn
  // pre-attention arena (inside olat region, dead before attn writes olat)
  bf16* xb     = (bf16*)(ws + 76021760);    // 2048x4096
  bf16* wqab   = (bf16*)(ws + 92798976);    // 1536x4096
  bf16* wkvabp = (bf16*)(ws + 105381888);   // 640x4096 padded
  bf16* qa     = (bf16*)(ws + 110624768);   // 2048x1536
  bf16* kvall  = (bf16*)(ws + 116916224);   // 2048x640
  bf16* qan    = (bf16*)(ws + 125829120);   // 2048x1536
  bf16* wqbb   = (bf16*)(ws + 76021760);    // 6144x1536 (after xb/wqab dead)
  bf16* qf     = (bf16*)(ws + 94896128);    // 2048x6144 (after qa/kvall dead)
  bf16* qnope  = (bf16*)(ws + 120061952);   // 2048x32x128 (after qan dead... written post-gemm2)
  bf16* wkvb1t = (bf16*)(ws + 76021760);    // 32x512x128 (after wqbb dead)
  // post-attention arena (inside qeffb region, dead after attn)
  bf16* wkvbv  = (bf16*)(ws + 524288);      // 32x128x512
  bf16* obuf   = (bf16*)(ws + 4718592);     // 2048x4096
  bf16* wob    = (bf16*)(ws + 21495808);    // 4096x4096

  // stage 1: casts + freqs
  cast_kernel<<<2048, 256, 0, stream>>>(x, xb, 2097152);
  cast_kernel<<<2048, 256, 0, stream>>>(wq_a, wqab, 1572864);
  cast_pad_kernel<<<2560, 256, 0, stream>>>(wkv_a, wkvabp);
  freqs_kernel<<<256, 256, 0, stream>>>(cosb, sinb);

  // stage 2: projections from x
  gemm_bt<bf16><<<dim3(12, 16, 1), 256, 0, stream>>>(xb, wqab, qa, 4096, 4096, 4096, 1536, 0, 0, 0);
  gemm_bt<bf16><<<dim3(5, 16, 1), 256, 0, stream>>>(xb, wkvabp, kvall, 4096, 4096, 4096, 640, 0, 0, 0);

  // stage 3: norms + k rope
  rmsnorm_bf_kernel<<<2048, 256, 0, stream>>>(qa, q_norm_w, qan, 1536, 1536, 1536);
  rmsnorm_bf_kernel<<<2048, 256, 0, stream>>>(kvall, kv_norm_w, keff, 512, 640, 576);
  rope_kpe_kernel<<<256, 256, 0, stream>>>(kvall, cosb, sinb, keff);

  // stage 4: q up-projection (wqbb aliases xb/wqab; qf aliases qa/kvall)
  cast_kernel<<<2048, 256, 0, stream>>>(wq_b, wqbb, 2359296);
  gemm_bt<bf16><<<dim3(48, 16, 1), 256, 0, stream>>>(qan, wqbb, qf, 1536, 1536, 1536, 6144, 0, 0, 0);

  // stage 5: q split + rope + latent projection
  qnope_cast_kernel<<<4096, 256, 0, stream>>>(qf, qnope);
  rope_q_kernel<<<8192, 256, 0, stream>>>(qf, cosb, sinb, qeffb);
  wkvbt_kernel<<<8192, 256, 0, stream>>>(wkv_b, wkvb1t);
  gemm_bt<bf16><<<dim3(4, 16, 32), 256, 0, stream>>>(qnope, wkvb1t, qeffb,
      128, 4096, 128, 18432, 128L, 65536L, 576L);

  // stage 6: attention (frees everything except olat)
  attn_kernel<<<dim3(32, 32), 256, 0, stream>>>(qeffb, keff, olat);

  // stage 7: per-head V projection (wkvbv/obuf alias dead qeffb)
  wkvbv_kernel<<<2048, 256, 0, stream>>>(wkv_b, wkvbv);
  gemm_bt<bf16><<<dim3(1, 16, 32), 256, 0, stream>>>(olat, wkvbv, obuf,
      512, 16384, 512, 4096, 512L, 65536L, 128L);

  // stage 8: output projection
  cast_kernel<<<2048, 256, 0, stream>>>(wo, wob, 4194304);
  gemm_bt<float><<<dim3(32, 16, 1), 256, 0, stream>>>(obuf, wob, (float*)d_out,
      4096, 4096, 4096, 4096, 0, 0, 0);
}